// Round 7
// baseline (250.061 us; speedup 1.0000x reference)
//
#include <hip/hip_runtime.h>

typedef unsigned short u16;
typedef unsigned int u32;

typedef __bf16 bf16x8 __attribute__((ext_vector_type(8)));
typedef _Float16 f16x8 __attribute__((ext_vector_type(8)));
typedef float f32x4 __attribute__((ext_vector_type(4)));
typedef float f32x16 __attribute__((ext_vector_type(16)));

typedef __attribute__((address_space(1))) u32 as1_u32;
typedef __attribute__((address_space(3))) u32 as3_u32;

#define EKF 0.18033688011112042f  // 0.125 * log2(e), folded into Q at GEMM1

__device__ __forceinline__ u16 f2bf(float x) {
  u32 u = __float_as_uint(x);
  u = u + 0x7fffu + ((u >> 16) & 1u);   // RNE
  return (u16)(u >> 16);
}
__device__ __forceinline__ u32 pack2(float a, float b) {
  return (u32)f2bf(a) | ((u32)f2bf(b) << 16);
}
__device__ __forceinline__ u32 pkf16(float a, float b) {
  return __builtin_bit_cast(u32, __builtin_amdgcn_cvt_pkrtz(a, b));
}
__device__ __forceinline__ u16 f2h(float a) {
  return (u16)(pkf16(a, a) & 0xffffu);
}
__device__ __forceinline__ void gld_lds16(const u16* g, const u16* l) {
  __builtin_amdgcn_global_load_lds((const as1_u32*)g, (as3_u32*)l, 16, 0, 0);
}

// ---------------- fused prepass: x cast + both weight transposes ----------------
// blocks 0..4095: cvt x -> bf16; 4096..4863: w_qkv^T; 4864..5119: w_out^T
__global__ __launch_bounds__(256) void prepass_kernel(const float* __restrict__ x,
                                                      const float* __restrict__ w_qkv,
                                                      const float* __restrict__ w_out,
                                                      u16* __restrict__ xb,
                                                      u16* __restrict__ wqkvT,
                                                      u16* __restrict__ woutT) {
  __shared__ float tile[64][65];
  int bid = blockIdx.x;
  int t = threadIdx.x;
  if (bid < 4096) {
    int i = bid * 256 + t;
    float4 v = ((const float4*)x)[i];
    uint2 r;
    r.x = pack2(v.x, v.y);
    r.y = pack2(v.z, v.w);
    ((uint2*)xb)[i] = r;
    return;
  }
  const float* W;
  u16* WT;
  int K, N, bx, by;
  if (bid < 4096 + 768) {
    int b2 = bid - 4096;
    W = w_qkv; WT = wqkvT; K = 1024; N = 3072; bx = b2 & 15; by = b2 >> 4;
  } else {
    int b2 = bid - 4864;
    W = w_out; WT = woutT; K = 1024; N = 1024; bx = b2 & 15; by = b2 >> 4;
  }
  int k0 = bx * 64, n0 = by * 64;
  int r = t >> 4, c4 = (t & 15) * 4;
#pragma unroll
  for (int i = 0; i < 4; ++i) {
    int row = r + i * 16;
    float4 v = *(const float4*)&W[(size_t)(k0 + row) * N + n0 + c4];
    tile[row][c4 + 0] = v.x; tile[row][c4 + 1] = v.y;
    tile[row][c4 + 2] = v.z; tile[row][c4 + 3] = v.w;
  }
  __syncthreads();
#pragma unroll
  for (int i = 0; i < 4; ++i) {
    int n = r + i * 16;
    uint2 o;
    o.x = pack2(tile[c4 + 0][n], tile[c4 + 1][n]);
    o.y = pack2(tile[c4 + 2][n], tile[c4 + 3][n]);
    *(uint2*)&WT[(size_t)(n0 + n) * K + k0 + c4] = o;
  }
}

// ---------------- f16 [4096][1024] -> vt[bh][d][j] tiled transpose ----------------
__global__ __launch_bounds__(256) void transpose_vt_kernel(const u16* __restrict__ vtmp,
                                                           u16* __restrict__ vt) {
  __shared__ u16 t[64 * 71];
  int j0 = blockIdx.x * 64;
  int bh = blockIdx.y;
  int b = bh >> 4, h = bh & 15;
  int tid = threadIdx.x;
  int r = tid >> 2, cs = (tid & 3) * 16;
  const u16* src = vtmp + (size_t)(b * 2048 + j0 + r) * 1024 + h * 64 + cs;
  uint4 a = ((const uint4*)src)[0];
  uint4 c = ((const uint4*)src)[1];
  u16* dst = &t[r * 71 + cs];
  dst[0] = (u16)a.x; dst[1] = (u16)(a.x >> 16); dst[2] = (u16)a.y; dst[3] = (u16)(a.y >> 16);
  dst[4] = (u16)a.z; dst[5] = (u16)(a.z >> 16); dst[6] = (u16)a.w; dst[7] = (u16)(a.w >> 16);
  dst[8] = (u16)c.x; dst[9] = (u16)(c.x >> 16); dst[10] = (u16)c.y; dst[11] = (u16)(c.y >> 16);
  dst[12] = (u16)c.z; dst[13] = (u16)(c.z >> 16); dst[14] = (u16)c.w; dst[15] = (u16)(c.w >> 16);
  __syncthreads();
  int d = tid >> 2, jseg = (tid & 3) * 16;
  u32 w[8];
#pragma unroll
  for (int i = 0; i < 8; ++i) {
    u32 lo = t[(jseg + 2 * i) * 71 + d];
    u32 hi = t[(jseg + 2 * i + 1) * 71 + d];
    w[i] = lo | (hi << 16);
  }
  u16* out = vt + (size_t)(bh * 64 + d) * 2048 + j0 + jseg;
  ((uint4*)out)[0] = make_uint4(w[0], w[1], w[2], w[3]);
  ((uint4*)out)[1] = make_uint4(w[4], w[5], w[6], w[7]);
}

// ---------------- bf16 GEMM: C[M,N] = A[M,K] * BT[N,K]^T ----------------
template <int OUT_MODE, int BN>
__global__ __launch_bounds__(256) void gemm_bt_kernel(const u16* __restrict__ A,
                                                      const u16* __restrict__ BT,
                                                      void* __restrict__ Cv,
                                                      u16* __restrict__ VT,
                                                      int M, int N, int K) {
  const int NF = (BN == 128) ? 4 : 2;
  __shared__ __attribute__((aligned(16))) u16 sA[128 * 32];
  __shared__ __attribute__((aligned(16))) u16 sB[BN * 32];
  const int tid = threadIdx.x;
  const int wave = tid >> 6;
  const int lane = tid & 63;
  const int bm = blockIdx.y * 128;
  const int bn = blockIdx.x * BN;
  const int wm = (wave >> 1) * 64;
  const int wn = (wave & 1) * (BN / 2);
  const int lr = lane & 15;
  const int kg = lane >> 4;

  const int srow = tid >> 2;
  const int scol = (tid & 3) * 8;
  const u16* pa0 = A + (size_t)(bm + srow) * K + scol;
  const u16* pa1 = pa0 + (size_t)64 * K;
  const u16* pb0 = BT + (size_t)(bn + srow) * K + scol;
  const u16* pb1 = pb0 + (size_t)64 * K;
  const u16* la = sA + wave * 512;
  const u16* lb = sB + wave * 512;

  f32x4 acc[4][NF];
#pragma unroll
  for (int i = 0; i < 4; i++)
#pragma unroll
    for (int j = 0; j < NF; j++) {
      f32x4 z = {0.f, 0.f, 0.f, 0.f};
      acc[i][j] = z;
    }

  for (int k0 = 0; k0 < K; k0 += 32) {
    __syncthreads();
    gld_lds16(pa0 + k0, la);
    gld_lds16(pa1 + k0, la + 2048);
    gld_lds16(pb0 + k0, lb);
    if (BN == 128) gld_lds16(pb1 + k0, lb + 2048);
    __syncthreads();
    bf16x8 af[4], bfr[NF];
#pragma unroll
    for (int mi = 0; mi < 4; mi++)
      af[mi] = *(const bf16x8*)(sA + (wm + mi * 16 + lr) * 32 + kg * 8);
#pragma unroll
    for (int ni = 0; ni < NF; ni++)
      bfr[ni] = *(const bf16x8*)(sB + (wn + ni * 16 + lr) * 32 + kg * 8);
#pragma unroll
    for (int mi = 0; mi < 4; mi++)
#pragma unroll
      for (int ni = 0; ni < NF; ni++)
        acc[mi][ni] = __builtin_amdgcn_mfma_f32_16x16x32_bf16(af[mi], bfr[ni], acc[mi][ni], 0, 0, 0);
  }

#pragma unroll
  for (int mi = 0; mi < 4; mi++)
#pragma unroll
    for (int ni = 0; ni < NF; ni++) {
      int c = bn + wn + ni * 16 + lr;
      int r0 = bm + wm + mi * 16 + kg * 4;
      if (OUT_MODE == 0) {
#pragma unroll
        for (int rr = 0; rr < 4; rr++)
          ((float*)Cv)[(size_t)(r0 + rr) * N + c] = acc[mi][ni][rr];
      } else {
        if (c < 1024) {
          u16* qkp = (u16*)Cv;
#pragma unroll
          for (int rr = 0; rr < 4; rr++)
            qkp[(size_t)(r0 + rr) * 2048 + c] = f2bf(acc[mi][ni][rr] * EKF);
        } else if (c < 2048) {
          u16* qkp = (u16*)Cv;
#pragma unroll
          for (int rr = 0; rr < 4; rr++)
            qkp[(size_t)(r0 + rr) * 2048 + c] = f2bf(acc[mi][ni][rr]);
        } else {
          int cc = c - 2048;
#pragma unroll
          for (int rr = 0; rr < 4; rr++)
            VT[(size_t)(r0 + rr) * 1024 + cc] = f2h(acc[mi][ni][rr]);
        }
      }
    }
}

// ---------------- MFMA flash attention v7 ----------------
// Grid-capped at 8 waves/CU (2048 waves total) -> minimize per-wave critical path:
// double-buffered LDS (one barrier/round, staging global loads prefetched into
// regs a full round ahead), P transformed C-layout -> B-frag via 8 shfl_xor(32)
// in registers (no LDS round-trip, no fence), V-frags hoisted before exp chain.
__global__ __launch_bounds__(128, 3) void attn_mfma_kernel(const u16* __restrict__ qk,
                                                           const u16* __restrict__ vt,
                                                           u16* __restrict__ out) {
  __shared__ __attribute__((aligned(16))) u16 sK[2][64 * 64];
  __shared__ __attribute__((aligned(16))) u16 sV[2][64 * 64];

  const int tid = threadIdx.x;
  const int wave = tid >> 6;
  const int lane = tid & 63;
  const int lq = lane & 31;   // q col (B n), j/d row (A m)
  const int g = lane >> 5;    // half-wave group
  const int l7 = lane & 7;    // XOR-swizzle key

  int idx = blockIdx.x;
  int qi = 31 - (idx >> 5);   // heavy q-tiles first
  int bh = idx & 31;
  int b = bh >> 4, h = bh & 15;
  int q0 = qi * 64;

  const u16* qbase = qk + (size_t)b * 2048 * 2048 + h * 64;
  const u16* kbase = qbase + 1024;
  const u16* vbase = vt + (size_t)bh * 64 * 2048;
  u16* obase = out + (size_t)b * 2048 * 1024 + h * 64;

  // Q fragments straight from global
  const int qcol = q0 + wave * 32 + lq;
  bf16x8 qf[4];
  {
    const u16* qrow = qbase + (size_t)qcol * 2048;
#pragma unroll
    for (int ks = 0; ks < 4; ++ks)
      qf[ks] = *(const bf16x8*)(qrow + ks * 16 + g * 8);
  }

  f32x16 oacc[2];
#pragma unroll
  for (int i = 0; i < 16; ++i) { oacc[0][i] = 0.f; oacc[1][i] = 0.f; }
  float lsum = 0.f;

  // staging: thread t -> row sr = t>>1, 64B half (t&1), 4 swizzled 16B chunks
  const int sr = tid >> 1;
  const int se = (tid & 1) * 32;
  const int sc0 = (tid & 1) * 4;
  const int sr7 = sr & 7;
  const u16* const kgp = kbase + (size_t)sr * 2048 + se;  // + t*64*2048 per round
  const u16* const vgp = vbase + (size_t)sr * 2048 + se;  // + t*64 per round

  const int smax = 2 * qi + wave;  // this wave's diagonal 32-j subtile index
  const int nrounds = qi + 1;

  uint4 kc[4], vc[4];
  // round 0: load + write buf0
#pragma unroll
  for (int i = 0; i < 4; ++i) kc[i] = ((const uint4*)kgp)[i];
#pragma unroll
  for (int i = 0; i < 4; ++i) vc[i] = ((const uint4*)vgp)[i];
#pragma unroll
  for (int i = 0; i < 4; ++i) {
    int ch = ((sc0 + i) ^ sr7) * 8;
    *(uint4*)(sK[0] + sr * 64 + ch) = kc[i];
    *(uint4*)(sV[0] + sr * 64 + ch) = vc[i];
  }
  // prefetch round 1 into regs
  if (nrounds > 1) {
#pragma unroll
    for (int i = 0; i < 4; ++i) kc[i] = ((const uint4*)(kgp + (size_t)64 * 2048))[i];
#pragma unroll
    for (int i = 0; i < 4; ++i) vc[i] = ((const uint4*)(vgp + 64))[i];
  }
  __syncthreads();

  for (int t = 0; t < nrounds; ++t) {
    const u16* sKb = sK[t & 1];
    const u16* sVb = sV[t & 1];

#pragma unroll
    for (int jt = 0; jt < 2; ++jt) {
      int s = 2 * t + jt;
      if (s > smax) continue;  // wave-uniform skip (fully masked)

      // S^T subtile: 32 j x 32 q
      f32x16 st;
#pragma unroll
      for (int i = 0; i < 16; ++i) st[i] = 0.f;
#pragma unroll
      for (int ks = 0; ks < 4; ++ks) {
        bf16x8 kf = *(const bf16x8*)(sKb + (jt * 32 + lq) * 64 + (((ks * 2 + g) ^ l7) * 8));
        st = __builtin_amdgcn_mfma_f32_32x32x16_bf16(kf, qf[ks], st, 0, 0, 0);
      }

      // V-frags early (independent of exp chain)
      f16x8 vf[4];
#pragma unroll
      for (int ks = 0; ks < 2; ++ks)
#pragma unroll
        for (int dt = 0; dt < 2; ++dt)
          vf[ks * 2 + dt] = *(const f16x8*)(sVb + (dt * 32 + lq) * 64 +
                                            (((jt * 4 + ks * 2 + g) ^ l7) * 8));

      float p[16];
      if (s == smax) {
#pragma unroll
        for (int a = 0; a < 16; ++a) {
          int jl = (a & 3) + 8 * (a >> 2) + 4 * g;  // j_local of reg a
          p[a] = (jl <= lq) ? exp2f(st[a]) : 0.f;
        }
      } else {
#pragma unroll
        for (int a = 0; a < 16; ++a) p[a] = exp2f(st[a]);
      }
#pragma unroll
      for (int a = 0; a < 16; ++a) lsum += p[a];

      // C-layout -> B-frag in registers: pack f16 pairs, swap halves via shfl
      u32 pk[8], pr[8];
#pragma unroll
      for (int i = 0; i < 8; ++i) pk[i] = pkf16(p[2 * i], p[2 * i + 1]);
#pragma unroll
      for (int i = 0; i < 8; ++i) pr[i] = __shfl_xor(pk[i], 32);
      // frag(ks) element e holds P[q=lq][j = ks*16 + g*8 + e]
      uint4 f0 = g ? make_uint4(pr[2], pr[3], pk[2], pk[3])
                   : make_uint4(pk[0], pk[1], pr[0], pr[1]);
      uint4 f1 = g ? make_uint4(pr[6], pr[7], pk[6], pk[7])
                   : make_uint4(pk[4], pk[5], pr[4], pr[5]);
      f16x8 pf0 = __builtin_bit_cast(f16x8, f0);
      f16x8 pf1 = __builtin_bit_cast(f16x8, f1);

      oacc[0] = __builtin_amdgcn_mfma_f32_32x32x16_f16(vf[0], pf0, oacc[0], 0, 0, 0);
      oacc[1] = __builtin_amdgcn_mfma_f32_32x32x16_f16(vf[1], pf0, oacc[1], 0, 0, 0);
      oacc[0] = __builtin_amdgcn_mfma_f32_32x32x16_f16(vf[2], pf1, oacc[0], 0, 0, 0);
      oacc[1] = __builtin_amdgcn_mfma_f32_32x32x16_f16(vf[3], pf1, oacc[1], 0, 0, 0);
    }

    // stage round t+1 (regs already loaded), prefetch t+2
    if (t + 1 < nrounds) {
      u16* dK = sK[(t + 1) & 1];
      u16* dV = sV[(t + 1) & 1];
#pragma unroll
      for (int i = 0; i < 4; ++i) {
        int ch = ((sc0 + i) ^ sr7) * 8;
        *(uint4*)(dK + sr * 64 + ch) = kc[i];
        *(uint4*)(dV + sr * 64 + ch) = vc[i];
      }
      if (t + 2 < nrounds) {
#pragma unroll
        for (int i = 0; i < 4; ++i)
          kc[i] = ((const uint4*)(kgp + (size_t)(t + 2) * 64 * 2048))[i];
#pragma unroll
        for (int i = 0; i < 4; ++i)
          vc[i] = ((const uint4*)(vgp + (size_t)(t + 2) * 64))[i];
      }
    }
    __syncthreads();
  }

  // l: combine the two half-wave j-partitions
  lsum += __shfl_xor(lsum, 32);
  float inv = 1.0f / lsum;

  // epilogue: O^T[d][q] -> out[q][d]; reg a -> d = dt*32 + 8*(a>>2) + 4*g + (a&3)
  u16* orow = obase + (size_t)qcol * 1024;
#pragma unroll
  for (int dt = 0; dt < 2; ++dt)
#pragma unroll
    for (int tq = 0; tq < 4; ++tq) {
      int d = dt * 32 + 8 * tq + 4 * g;
      uint2 o2 = make_uint2(pack2(oacc[dt][4 * tq + 0] * inv, oacc[dt][4 * tq + 1] * inv),
                            pack2(oacc[dt][4 * tq + 2] * inv, oacc[dt][4 * tq + 3] * inv));
      *(uint2*)(orow + d) = o2;
    }
}

// ---------------- launch ----------------
extern "C" void kernel_launch(void* const* d_in, const int* in_sizes, int n_in,
                              void* d_out, int out_size, void* d_ws, size_t ws_size,
                              hipStream_t stream) {
  const float* x = (const float*)d_in[0];      // [2,2048,1024]
  const float* w_qkv = (const float*)d_in[1];  // [1024,3072]
  const float* w_out = (const float*)d_in[2];  // [1024,1024]
  float* out = (float*)d_out;                  // [2,2048,1024] fp32

  char* ws = (char*)d_ws;
  u16* xb    = (u16*)(ws);                //  8 MB: x bf16 [4096,1024]
  u16* wqkvT = (u16*)(ws + (8u << 20));   //  6 MB: w_qkv^T bf16 [3072,1024]
  u16* woutT = (u16*)(ws + (14u << 20));  //  2 MB: w_out^T bf16 [1024,1024]
  u16* qkb   = (u16*)(ws + (16u << 20));  // 16 MB: q|k bf16 [4096,2048]
  u16* vtb   = (u16*)(ws + (32u << 20));  //  8 MB: V^T f16 [32,64,2048]
  u16* vtmp  = (u16*)(ws + (40u << 20));  //  8 MB: v f16 [4096,1024] (dead after
  u16* attn  = (u16*)(ws + (40u << 20));  //        transpose_vt; region reused)

  prepass_kernel<<<5120, 256, 0, stream>>>(x, w_qkv, w_out, xb, wqkvT, woutT);

  gemm_bt_kernel<2, 128><<<dim3(3072 / 128, 4096 / 128), 256, 0, stream>>>(
      xb, wqkvT, (void*)qkb, vtmp, 4096, 3072, 1024);

  transpose_vt_kernel<<<dim3(32, 32), 256, 0, stream>>>(vtmp, vtb);

  attn_mfma_kernel<<<1024, 128, 0, stream>>>(qkb, vtb, attn);

  gemm_bt_kernel<0, 64><<<dim3(1024 / 64, 4096 / 128), 256, 0, stream>>>(
      attn, woutT, (void*)out, nullptr, 4096, 1024, 1024);
}

// Round 8
// 183.116 us; speedup vs baseline: 1.3656x; 1.3656x over previous
//
#include <hip/hip_runtime.h>

typedef unsigned short u16;
typedef unsigned int u32;

typedef __bf16 bf16x8 __attribute__((ext_vector_type(8)));
typedef _Float16 f16x8 __attribute__((ext_vector_type(8)));
typedef float f32x4 __attribute__((ext_vector_type(4)));

typedef __attribute__((address_space(1))) u32 as1_u32;
typedef __attribute__((address_space(3))) u32 as3_u32;

#define EKF 0.18033688011112042f  // 0.125 * log2(e), folded into Q at GEMM1

__device__ __forceinline__ u16 f2bf(float x) {
  u32 u = __float_as_uint(x);
  u = u + 0x7fffu + ((u >> 16) & 1u);   // RNE
  return (u16)(u >> 16);
}
__device__ __forceinline__ u32 pack2(float a, float b) {
  return (u32)f2bf(a) | ((u32)f2bf(b) << 16);
}
__device__ __forceinline__ u32 pkf16(float a, float b) {
  return __builtin_bit_cast(u32, __builtin_amdgcn_cvt_pkrtz(a, b));
}
__device__ __forceinline__ u16 f2h(float a) {
  return (u16)(pkf16(a, a) & 0xffffu);
}
__device__ __forceinline__ void gld_lds16(const u16* g, const u16* l) {
  __builtin_amdgcn_global_load_lds((const as1_u32*)g, (as3_u32*)l, 16, 0, 0);
}

// ---------------- fused prepass: x cast + both weight transposes ----------------
__global__ __launch_bounds__(256) void prepass_kernel(const float* __restrict__ x,
                                                      const float* __restrict__ w_qkv,
                                                      const float* __restrict__ w_out,
                                                      u16* __restrict__ xb,
                                                      u16* __restrict__ wqkvT,
                                                      u16* __restrict__ woutT) {
  __shared__ float tile[64][65];
  int bid = blockIdx.x;
  int t = threadIdx.x;
  if (bid < 4096) {
    int i = bid * 256 + t;
    float4 v = ((const float4*)x)[i];
    uint2 r;
    r.x = pack2(v.x, v.y);
    r.y = pack2(v.z, v.w);
    ((uint2*)xb)[i] = r;
    return;
  }
  const float* W;
  u16* WT;
  int K, N, bx, by;
  if (bid < 4096 + 768) {
    int b2 = bid - 4096;
    W = w_qkv; WT = wqkvT; K = 1024; N = 3072; bx = b2 & 15; by = b2 >> 4;
  } else {
    int b2 = bid - 4864;
    W = w_out; WT = woutT; K = 1024; N = 1024; bx = b2 & 15; by = b2 >> 4;
  }
  int k0 = bx * 64, n0 = by * 64;
  int r = t >> 4, c4 = (t & 15) * 4;
#pragma unroll
  for (int i = 0; i < 4; ++i) {
    int row = r + i * 16;
    float4 v = *(const float4*)&W[(size_t)(k0 + row) * N + n0 + c4];
    tile[row][c4 + 0] = v.x; tile[row][c4 + 1] = v.y;
    tile[row][c4 + 2] = v.z; tile[row][c4 + 3] = v.w;
  }
  __syncthreads();
#pragma unroll
  for (int i = 0; i < 4; ++i) {
    int n = r + i * 16;
    uint2 o;
    o.x = pack2(tile[c4 + 0][n], tile[c4 + 1][n]);
    o.y = pack2(tile[c4 + 2][n], tile[c4 + 3][n]);
    *(uint2*)&WT[(size_t)(n0 + n) * K + k0 + c4] = o;
  }
}

// ---------------- f16 [4096][1024] -> vt[bh][d][j] tiled transpose ----------------
__global__ __launch_bounds__(256) void transpose_vt_kernel(const u16* __restrict__ vtmp,
                                                           u16* __restrict__ vt) {
  __shared__ u16 t[64 * 71];
  int j0 = blockIdx.x * 64;
  int bh = blockIdx.y;
  int b = bh >> 4, h = bh & 15;
  int tid = threadIdx.x;
  int r = tid >> 2, cs = (tid & 3) * 16;
  const u16* src = vtmp + (size_t)(b * 2048 + j0 + r) * 1024 + h * 64 + cs;
  uint4 a = ((const uint4*)src)[0];
  uint4 c = ((const uint4*)src)[1];
  u16* dst = &t[r * 71 + cs];
  dst[0] = (u16)a.x; dst[1] = (u16)(a.x >> 16); dst[2] = (u16)a.y; dst[3] = (u16)(a.y >> 16);
  dst[4] = (u16)a.z; dst[5] = (u16)(a.z >> 16); dst[6] = (u16)a.w; dst[7] = (u16)(a.w >> 16);
  dst[8] = (u16)c.x; dst[9] = (u16)(c.x >> 16); dst[10] = (u16)c.y; dst[11] = (u16)(c.y >> 16);
  dst[12] = (u16)c.z; dst[13] = (u16)(c.z >> 16); dst[14] = (u16)c.w; dst[15] = (u16)(c.w >> 16);
  __syncthreads();
  int d = tid >> 2, jseg = (tid & 3) * 16;
  u32 w[8];
#pragma unroll
  for (int i = 0; i < 8; ++i) {
    u32 lo = t[(jseg + 2 * i) * 71 + d];
    u32 hi = t[(jseg + 2 * i + 1) * 71 + d];
    w[i] = lo | (hi << 16);
  }
  u16* out = vt + (size_t)(bh * 64 + d) * 2048 + j0 + jseg;
  ((uint4*)out)[0] = make_uint4(w[0], w[1], w[2], w[3]);
  ((uint4*)out)[1] = make_uint4(w[4], w[5], w[6], w[7]);
}

// ---------------- bf16 GEMM: C[M,N] = A[M,K] * BT[N,K]^T ----------------
template <int OUT_MODE, int BN>
__global__ __launch_bounds__(256) void gemm_bt_kernel(const u16* __restrict__ A,
                                                      const u16* __restrict__ BT,
                                                      void* __restrict__ Cv,
                                                      u16* __restrict__ VT,
                                                      int M, int N, int K) {
  const int NF = (BN == 128) ? 4 : 2;
  __shared__ __attribute__((aligned(16))) u16 sA[128 * 32];
  __shared__ __attribute__((aligned(16))) u16 sB[BN * 32];
  const int tid = threadIdx.x;
  const int wave = tid >> 6;
  const int lane = tid & 63;
  const int bm = blockIdx.y * 128;
  const int bn = blockIdx.x * BN;
  const int wm = (wave >> 1) * 64;
  const int wn = (wave & 1) * (BN / 2);
  const int lr = lane & 15;
  const int kg = lane >> 4;

  const int srow = tid >> 2;
  const int scol = (tid & 3) * 8;
  const u16* pa0 = A + (size_t)(bm + srow) * K + scol;
  const u16* pa1 = pa0 + (size_t)64 * K;
  const u16* pb0 = BT + (size_t)(bn + srow) * K + scol;
  const u16* pb1 = pb0 + (size_t)64 * K;
  const u16* la = sA + wave * 512;
  const u16* lb = sB + wave * 512;

  f32x4 acc[4][NF];
#pragma unroll
  for (int i = 0; i < 4; i++)
#pragma unroll
    for (int j = 0; j < NF; j++) {
      f32x4 z = {0.f, 0.f, 0.f, 0.f};
      acc[i][j] = z;
    }

  for (int k0 = 0; k0 < K; k0 += 32) {
    __syncthreads();
    gld_lds16(pa0 + k0, la);
    gld_lds16(pa1 + k0, la + 2048);
    gld_lds16(pb0 + k0, lb);
    if (BN == 128) gld_lds16(pb1 + k0, lb + 2048);
    __syncthreads();
    bf16x8 af[4], bfr[NF];
#pragma unroll
    for (int mi = 0; mi < 4; mi++)
      af[mi] = *(const bf16x8*)(sA + (wm + mi * 16 + lr) * 32 + kg * 8);
#pragma unroll
    for (int ni = 0; ni < NF; ni++)
      bfr[ni] = *(const bf16x8*)(sB + (wn + ni * 16 + lr) * 32 + kg * 8);
#pragma unroll
    for (int mi = 0; mi < 4; mi++)
#pragma unroll
      for (int ni = 0; ni < NF; ni++)
        acc[mi][ni] = __builtin_amdgcn_mfma_f32_16x16x32_bf16(af[mi], bfr[ni], acc[mi][ni], 0, 0, 0);
  }

#pragma unroll
  for (int mi = 0; mi < 4; mi++)
#pragma unroll
    for (int ni = 0; ni < NF; ni++) {
      int c = bn + wn + ni * 16 + lr;
      int r0 = bm + wm + mi * 16 + kg * 4;
      if (OUT_MODE == 0) {
#pragma unroll
        for (int rr = 0; rr < 4; rr++)
          ((float*)Cv)[(size_t)(r0 + rr) * N + c] = acc[mi][ni][rr];
      } else {
        if (c < 1024) {
          u16* qkp = (u16*)Cv;
#pragma unroll
          for (int rr = 0; rr < 4; rr++)
            qkp[(size_t)(r0 + rr) * 2048 + c] = f2bf(acc[mi][ni][rr] * EKF);
        } else if (c < 2048) {
          u16* qkp = (u16*)Cv;
#pragma unroll
          for (int rr = 0; rr < 4; rr++)
            qkp[(size_t)(r0 + rr) * 2048 + c] = f2bf(acc[mi][ni][rr]);
        } else {
          int cc = c - 2048;
#pragma unroll
          for (int rr = 0; rr < 4; rr++)
            VT[(size_t)(r0 + rr) * 1024 + cc] = f2h(acc[mi][ni][rr]);
        }
      }
    }
}

// ---------------- MFMA flash attention v8 ----------------
// 16x16 shapes (16 q/wave -> 4096 waves = 16 waves/CU), double-buffered K/V
// staged by global_load_lds (zero VGPR cost) with the XOR swizzle applied to the
// GLOBAL source address; prefetch issued before compute -> one barrier/round.
// LDS 40 KB -> 4 blocks/CU. Mask/zero work only in the final (diagonal) round.
__global__ __launch_bounds__(256, 4) void attn_mfma_kernel(const u16* __restrict__ qk,
                                                           const u16* __restrict__ vt,
                                                           u16* __restrict__ out) {
  __shared__ __attribute__((aligned(16))) u16 sK[2][64 * 64];  // [j][d] swizzled
  __shared__ __attribute__((aligned(16))) u16 sV[2][64 * 64];  // [d][j] swizzled
  __shared__ __attribute__((aligned(16))) u16 sP[4][16 * 64];  // [q][j] 8B-swizzled

  const int tid = threadIdx.x;
  const int wave = tid >> 6;
  const int lane = tid & 63;
  const int lr = lane & 15;  // q col (B), j/d row (A)
  const int kg = lane >> 4;  // k-group / row-quad
  const int l7 = lr & 7;

  int idx = blockIdx.x;
  int qi = 31 - (idx >> 5);  // heavy q-tiles first
  int bh = idx & 31;
  int b = bh >> 4, h = bh & 15;
  int q0 = qi * 64;

  const u16* qbase = qk + (size_t)b * 2048 * 2048 + h * 64;
  const u16* kbase = qbase + 1024;
  const u16* vbase = vt + (size_t)bh * 64 * 2048;
  u16* obase = out + (size_t)b * 2048 * 1024 + h * 64;

  // staging maps: instr (wave,i) covers LDS chunks [(wave*2+i)*64, +64) = rows
  // wave*16+i*8 + (lane>>3), chunk c=lane&7; global chunk = c ^ (row&7).
  const int sra = wave * 16 + (lane >> 3);
  const int srb = sra + 8;
  const int sc = lane & 7;
  const u32 koffA = (u32)sra * 2048 + (u32)((sc ^ (sra & 7)) * 8);
  const u32 koffB = (u32)srb * 2048 + (u32)((sc ^ (srb & 7)) * 8);
  const u32 ldsA = (wave * 2 + 0) * 512;  // u16 elements
  const u32 ldsB = (wave * 2 + 1) * 512;

  // Q fragments straight from global (2 x b128 per lane, once)
  const int qcol = q0 + wave * 16 + lr;
  bf16x8 qf0, qf1;
  {
    const u16* qrow = qbase + (size_t)qcol * 2048;
    qf0 = *(const bf16x8*)(qrow + kg * 8);
    qf1 = *(const bf16x8*)(qrow + 32 + kg * 8);
  }

  // frag read offsets (u16): row lr, swizzled chunk; +jt*1024 / +dt*1024
  const u32 ka0 = (u32)(lr * 64 + ((kg ^ l7) * 8));
  const u32 ka1 = (u32)(lr * 64 + (((4 + kg) ^ l7) * 8));
  u16* const sPw = sP[wave];
  const u32 pr0 = (u32)(lr * 64 + (((kg * 2) ^ (l7 << 1)) * 4));
  const u32 pr1 = (u32)(lr * 64 + (((8 + kg * 2) ^ (l7 << 1)) * 4));

  f32x4 oacc[4];
#pragma unroll
  for (int i = 0; i < 4; ++i) {
    f32x4 z = {0.f, 0.f, 0.f, 0.f};
    oacc[i] = z;
  }
  float lsum = 0.f;

  const int nrounds = qi + 1;
  // prologue: stage round 0 into buf 0
  gld_lds16(kbase + koffA, sK[0] + ldsA);
  gld_lds16(kbase + koffB, sK[0] + ldsB);
  gld_lds16(vbase + koffA, sV[0] + ldsA);
  gld_lds16(vbase + koffB, sV[0] + ldsB);
  __syncthreads();

  for (int t = 0; t < nrounds; ++t) {
    // prefetch round t+1 into the other buffer (overlaps this round's compute)
    if (t + 1 < nrounds) {
      int j1 = (t + 1) * 64;
      u16* dK = sK[(t + 1) & 1];
      u16* dV = sV[(t + 1) & 1];
      gld_lds16(kbase + (size_t)j1 * 2048 + koffA, dK + ldsA);
      gld_lds16(kbase + (size_t)j1 * 2048 + koffB, dK + ldsB);
      gld_lds16(vbase + j1 + koffA, dV + ldsA);
      gld_lds16(vbase + j1 + koffB, dV + ldsB);
    }
    const u16* sKb = sK[t & 1];
    const u16* sVb = sV[t & 1];
    const bool diag = (t == qi);

#pragma unroll
    for (int jt = 0; jt < 4; ++jt) {
      u16* pw = sPw + lr * 64 + (((jt * 4 + kg) ^ (l7 << 1)) * 4);
      if (!diag || jt <= wave) {
        bf16x8 kf0 = *(const bf16x8*)(sKb + jt * 1024 + ka0);
        bf16x8 kf1 = *(const bf16x8*)(sKb + jt * 1024 + ka1);
        f32x4 c = {0.f, 0.f, 0.f, 0.f};
        c = __builtin_amdgcn_mfma_f32_16x16x32_bf16(kf0, qf0, c, 0, 0, 0);
        c = __builtin_amdgcn_mfma_f32_16x16x32_bf16(kf1, qf1, c, 0, 0, 0);
        float p0 = exp2f(c[0]);
        float p1 = exp2f(c[1]);
        float p2 = exp2f(c[2]);
        float p3 = exp2f(c[3]);
        if (diag && jt == wave) {  // diagonal subtile: j_local = kg*4+r vs q_local = lr
          int jr = kg * 4;
          p0 = (jr + 0 <= lr) ? p0 : 0.f;
          p1 = (jr + 1 <= lr) ? p1 : 0.f;
          p2 = (jr + 2 <= lr) ? p2 : 0.f;
          p3 = (jr + 3 <= lr) ? p3 : 0.f;
        }
        lsum += (p0 + p1) + (p2 + p3);
        *(uint2*)pw = make_uint2(pkf16(p0, p1), pkf16(p2, p3));
      } else {
        *(uint2*)pw = make_uint2(0u, 0u);
      }
    }

    asm volatile("" ::: "memory");  // P writes precede P-frag reads (same wave)

    f16x8 pf0 = *(const f16x8*)(sPw + pr0);
    f16x8 pf1 = *(const f16x8*)(sPw + pr1);
#pragma unroll
    for (int dt = 0; dt < 4; ++dt) {
      f16x8 vf0 = *(const f16x8*)(sVb + dt * 1024 + ka0);
      f16x8 vf1 = *(const f16x8*)(sVb + dt * 1024 + ka1);
      oacc[dt] = __builtin_amdgcn_mfma_f32_16x16x32_f16(vf0, pf0, oacc[dt], 0, 0, 0);
      oacc[dt] = __builtin_amdgcn_mfma_f32_16x16x32_f16(vf1, pf1, oacc[dt], 0, 0, 0);
    }
    __syncthreads();  // drains prefetch (covered by compute) + protects buffers
  }

  // l: reduce across the 4 row-quad groups sharing q column
  lsum += __shfl_xor(lsum, 16);
  lsum += __shfl_xor(lsum, 32);
  float inv = 1.0f / lsum;

  // epilogue: O^T[d][q] -> out[q][d]; d = dt*16 + kg*4 + rr
  u16* orow = obase + (size_t)qcol * 1024;
#pragma unroll
  for (int dt = 0; dt < 4; ++dt) {
    uint2 o2 = make_uint2(pack2(oacc[dt][0] * inv, oacc[dt][1] * inv),
                          pack2(oacc[dt][2] * inv, oacc[dt][3] * inv));
    *(uint2*)(orow + dt * 16 + kg * 4) = o2;
  }
}

// ---------------- launch ----------------
extern "C" void kernel_launch(void* const* d_in, const int* in_sizes, int n_in,
                              void* d_out, int out_size, void* d_ws, size_t ws_size,
                              hipStream_t stream) {
  const float* x = (const float*)d_in[0];      // [2,2048,1024]
  const float* w_qkv = (const float*)d_in[1];  // [1024,3072]
  const float* w_out = (const float*)d_in[2];  // [1024,1024]
  float* out = (float*)d_out;                  // [2,2048,1024] fp32

  char* ws = (char*)d_ws;
  u16* xb    = (u16*)(ws);                //  8 MB: x bf16 [4096,1024]
  u16* wqkvT = (u16*)(ws + (8u << 20));   //  6 MB: w_qkv^T bf16 [3072,1024]
  u16* woutT = (u16*)(ws + (14u << 20));  //  2 MB: w_out^T bf16 [1024,1024]
  u16* qkb   = (u16*)(ws + (16u << 20));  // 16 MB: q|k bf16 [4096,2048]
  u16* vtb   = (u16*)(ws + (32u << 20));  //  8 MB: V^T f16 [32,64,2048]
  u16* vtmp  = (u16*)(ws + (40u << 20));  //  8 MB: v f16 [4096,1024] (dead after
  u16* attn  = (u16*)(ws + (40u << 20));  //        transpose_vt; region reused)

  prepass_kernel<<<5120, 256, 0, stream>>>(x, w_qkv, w_out, xb, wqkvT, woutT);

  gemm_bt_kernel<2, 128><<<dim3(3072 / 128, 4096 / 128), 256, 0, stream>>>(
      xb, wqkvT, (void*)qkb, vtmp, 4096, 3072, 1024);

  transpose_vt_kernel<<<dim3(32, 32), 256, 0, stream>>>(vtmp, vtb);

  attn_mfma_kernel<<<1024, 256, 0, stream>>>(qkb, vtb, attn);

  gemm_bt_kernel<0, 64><<<dim3(1024 / 64, 4096 / 128), 256, 0, stream>>>(
      attn, woutT, (void*)out, nullptr, 4096, 1024, 1024);
}